// Round 1
// 527.862 us; speedup vs baseline: 1.0662x; 1.0662x over previous
//
#include <hip/hip_runtime.h>
#include <stdint.h>

#define NP 8192           // particles
#define NC 8192           // channels

__host__ __device__ inline uint32_t rotl32(uint32_t x, int r) {
  return __builtin_rotateleft32(x, (unsigned)r);   // v_alignbit_b32 on gfx950
}

// JAX threefry2x32: 20 rounds, key schedule injection every 4 rounds.
__host__ __device__ inline void threefry2x32(uint32_t k0, uint32_t k1,
                                             uint32_t x0, uint32_t x1,
                                             uint32_t& o0, uint32_t& o1) {
  uint32_t ks2 = k0 ^ k1 ^ 0x1BD11BDAu;
  x0 += k0; x1 += k1;
#define TF_R(r) { x0 += x1; x1 = rotl32(x1, (r)); x1 ^= x0; }
  TF_R(13) TF_R(15) TF_R(26) TF_R(6)   x0 += k1;  x1 += ks2 + 1u;
  TF_R(17) TF_R(29) TF_R(16) TF_R(24)  x0 += ks2; x1 += k0 + 2u;
  TF_R(13) TF_R(15) TF_R(26) TF_R(6)   x0 += k0;  x1 += k1 + 3u;
  TF_R(17) TF_R(29) TF_R(16) TF_R(24)  x0 += k1;  x1 += ks2 + 4u;
  TF_R(13) TF_R(15) TF_R(26) TF_R(6)   x0 += ks2; x1 += k0 + 5u;
#undef TF_R
  o0 = x0; o1 = x1;
}

// partitionable threefry random_bits, 32-bit: counter=(0,i), bits = o0 ^ o1
__device__ inline uint32_t tf_bits(uint32_t k0, uint32_t k1, uint32_t i) {
  uint32_t o0, o1;
  threefry2x32(k0, k1, 0u, i, o0, o1);
  return o0 ^ o1;
}

// uniform [0,1): (bits>>9)|0x3f800000 -> [1,2) -> -1
__device__ inline float u01(uint32_t bits) {
  return __uint_as_float((bits >> 9) | 0x3f800000u) - 1.0f;
}

// E = -log(uniform(tiny,1)) — the winv-independent part of the race value.
// NOTE: (-logf(v)) * winv == -(logf(v) * winv) exactly in IEEE (negation is
// exact), so splitting E out preserves the argmin winner bit-for-bit.
__device__ inline float egen(uint32_t k0, uint32_t k1, uint32_t ctr) {
  const float TINY = 1.17549435e-38f;
  uint32_t bits = tf_bits(k0, k1, ctr);
  float v = fmaxf(u01(bits), TINY);
  return -__logf(v);  // native v_log_f32 * ln2, same expression as before
}

// XLA ErfInv32 (Giles) polynomial
__device__ inline float erfinvf_(float x) {
  float w = -log1pf(-x * x);
  float p;
  if (w < 5.0f) {
    w -= 2.5f;
    p = 2.81022636e-08f;
    p = fmaf(p, w, 3.43273939e-07f);
    p = fmaf(p, w, -3.5233877e-06f);
    p = fmaf(p, w, -4.39150654e-06f);
    p = fmaf(p, w, 0.00021858087f);
    p = fmaf(p, w, -0.00125372503f);
    p = fmaf(p, w, -0.00417768164f);
    p = fmaf(p, w, 0.246640727f);
    p = fmaf(p, w, 1.50140941f);
  } else {
    w = sqrtf(w) - 3.0f;
    p = -0.000200214257f;
    p = fmaf(p, w, 0.000100950558f);
    p = fmaf(p, w, 0.00134934322f);
    p = fmaf(p, w, -0.00367342844f);
    p = fmaf(p, w, 0.00573950773f);
    p = fmaf(p, w, -0.0076224613f);
    p = fmaf(p, w, 0.00943887047f);
    p = fmaf(p, w, 1.00167406f);
    p = fmaf(p, w, 2.83297682f);
  }
  return p * x;
}

// Fused: blocks 0..31 -> state = sv@T^T + z@chol(Q) (z regenerated per thread);
//        blocks 32..127 -> Ht (column-major transpose of H, 3 x 8192)
__global__ void __launch_bounds__(256) k_prep(uint32_t k0, uint32_t k1,
                                              const float* __restrict__ sv,
                                              const float* __restrict__ T,
                                              const float* __restrict__ Q,
                                              const float* __restrict__ H,
                                              float* __restrict__ st,
                                              float* __restrict__ ht) {
  int b = blockIdx.x;
  if (b < 32) {
    int i = b * 256 + threadIdx.x;  // particle
    const float lo = -0.99999994f;  // nextafter(-1,0)
    float zz[3];
#pragma unroll
    for (int k = 0; k < 3; k++) {
      uint32_t bits = tf_bits(k0, k1, 3u * (uint32_t)i + (uint32_t)k);
      float v = fmaxf(lo, u01(bits) * 2.0f + lo);  // span fp32(1-lo) == 2.0
      zz[k] = 1.41421356f * erfinvf_(v);           // fp32(sqrt(2))
    }
    float L00 = sqrtf(Q[0]);
    float L10 = Q[3] / L00, L20 = Q[6] / L00;
    float L11 = sqrtf(Q[4] - L10 * L10);
    float L21 = (Q[7] - L20 * L10) / L11;
    float L22 = sqrtf(Q[8] - L20 * L20 - L21 * L21);
    float s0 = sv[i * 3], s1 = sv[i * 3 + 1], s2 = sv[i * 3 + 2];
    float u0 = s0 * T[0] + s1 * T[1] + s2 * T[2];
    float u1 = s0 * T[3] + s1 * T[4] + s2 * T[5];
    float u2 = s0 * T[6] + s1 * T[7] + s2 * T[8];
    st[i * 3]     = u0 + (zz[0] * L00 + zz[1] * L10 + zz[2] * L20);
    st[i * 3 + 1] = u1 + (zz[1] * L11 + zz[2] * L21);
    st[i * 3 + 2] = u2 + (zz[2] * L22);
  } else {
    int t = (b - 32) * 256 + threadIdx.x;  // 0..24575
    int k = t >> 13, j = t & (NP - 1);
    ht[t] = H[j * 3 + k];  // ht[k*8192 + j] = H[j][k]
  }
}

// ---------------- fused path: weights (HBM-bound) || RNG E-gen (VALU-bound) ---
// 10240 blocks: b%5==0 -> weights group w=b/5 (rows 4w..4w+3),
//               else   -> RNG sample s = b - b/5 - 1, writes E row (float4).
// Interleaving roles keeps both pipes busy from dispatch onward; the 256 MB
// weights stream + 256 MB E-write ride under ~190 us of VALU-bound hashing.
__global__ void __launch_bounds__(256) k_fused(uint32_t k0, uint32_t k1,
                                               const float* __restrict__ in,
                                               const float* __restrict__ ht,
                                               const float* __restrict__ st,
                                               float* __restrict__ winv,
                                               float* __restrict__ E) {
  int b = blockIdx.x;
  if (b % 5 == 0) {
    // ---- weights role (identical math to old k_weights) ----
    int w = b / 5;
    int wave = threadIdx.x >> 6;
    int lane = threadIdx.x & 63;
    int row = w * 4 + wave;
    float s0 = st[row * 3], s1 = st[row * 3 + 1], s2 = st[row * 3 + 2];
    const float4* inrow = (const float4*)(in + (size_t)row * NC);
    const float4* h0 = (const float4*)ht;
    const float4* h1 = (const float4*)(ht + NC);
    const float4* h2 = (const float4*)(ht + 2 * NC);
    float acc = 0.0f;
#pragma unroll 4
    for (int it = lane; it < NC / 4; it += 64) {
      float4 x = inrow[it];
      float4 a = h0[it];
      float4 bb = h1[it];
      float4 c = h2[it];
      float d0 = x.x - (a.x * s0 + bb.x * s1 + c.x * s2);
      float d1 = x.y - (a.y * s0 + bb.y * s1 + c.y * s2);
      float d2 = x.z - (a.z * s0 + bb.z * s1 + c.z * s2);
      float d3 = x.w - (a.w * s0 + bb.w * s1 + c.w * s2);
      acc += d0 * d0 + d1 * d1 + d2 * d2 + d3 * d3;
    }
#pragma unroll
    for (int off = 32; off > 0; off >>= 1) acc += __shfl_down(acc, off, 64);
    if (lane == 0) winv[row] = 1.0f / acc;
  } else {
    // ---- RNG role: E[s][i] = -log(u_{s,i}), 4 consecutive i per thread ----
    int s = b - b / 5 - 1;                  // 0..8191
    uint32_t base = (uint32_t)s * (uint32_t)NP;
    float4* erow = (float4*)(E + (size_t)s * NP);
#pragma unroll 2
    for (int p = 0; p < 8; ++p) {
      uint32_t i0 = (uint32_t)(p * 1024 + 4 * threadIdx.x);
      float4 e;
      e.x = egen(k0, k1, base + i0);
      e.y = egen(k0, k1, base + i0 + 1u);
      e.z = egen(k0, k1, base + i0 + 2u);
      e.w = egen(k0, k1, base + i0 + 3u);
      erow[i0 >> 2] = e;
    }
  }
}

// Race finish: idx[s] = argmin_i E[s][i] * winv[i], lowest index on ties
// (per-thread ascending strict <, cross-lane explicit index tie-break —
//  identical winner semantics to the old k_resample). One wave per sample.
__global__ void __launch_bounds__(256) k_race(const float* __restrict__ E,
                                              const float* __restrict__ winv,
                                              int* __restrict__ idx) {
  int wave = threadIdx.x >> 6;
  int lane = threadIdx.x & 63;
  int s = blockIdx.x * 4 + wave;
  const float4* erow = (const float4*)(E + (size_t)s * NP);
  const float4* wv = (const float4*)winv;
  float best = 3.4e38f;
  int bi = 0;
#pragma unroll 4
  for (int it = lane; it < NP / 4; it += 64) {
    float4 e = erow[it];
    float4 w = wv[it];
    int i = it * 4;
    float r0 = e.x * w.x;
    float r1 = e.y * w.y;
    float r2 = e.z * w.z;
    float r3 = e.w * w.w;
    if (r0 < best) { best = r0; bi = i; }
    if (r1 < best) { best = r1; bi = i + 1; }
    if (r2 < best) { best = r2; bi = i + 2; }
    if (r3 < best) { best = r3; bi = i + 3; }
  }
#pragma unroll
  for (int off = 32; off > 0; off >>= 1) {
    float ob = __shfl_down(best, off, 64);
    int oi = __shfl_down(bi, off, 64);
    if (ob < best || (ob == best && oi < bi)) { best = ob; bi = oi; }
  }
  if (lane == 0) idx[s] = bi;
}

// ---------------- fallback path (ws too small): original kernels --------------
__global__ void __launch_bounds__(256) k_weights(const float* __restrict__ in,
                                                 const float* __restrict__ ht,
                                                 const float* __restrict__ st,
                                                 float* __restrict__ winv) {
  int wave = threadIdx.x >> 6;
  int lane = threadIdx.x & 63;
  int row = blockIdx.x * 4 + wave;
  float s0 = st[row * 3], s1 = st[row * 3 + 1], s2 = st[row * 3 + 2];
  const float4* inrow = (const float4*)(in + (size_t)row * NC);
  const float4* h0 = (const float4*)ht;
  const float4* h1 = (const float4*)(ht + NC);
  const float4* h2 = (const float4*)(ht + 2 * NC);
  float acc = 0.0f;
#pragma unroll 4
  for (int it = lane; it < NC / 4; it += 64) {
    float4 x = inrow[it];
    float4 a = h0[it];
    float4 b = h1[it];
    float4 c = h2[it];
    float d0 = x.x - (a.x * s0 + b.x * s1 + c.x * s2);
    float d1 = x.y - (a.y * s0 + b.y * s1 + c.y * s2);
    float d2 = x.z - (a.z * s0 + b.z * s1 + c.z * s2);
    float d3 = x.w - (a.w * s0 + b.w * s1 + c.w * s2);
    acc += d0 * d0 + d1 * d1 + d2 * d2 + d3 * d3;
  }
#pragma unroll
  for (int off = 32; off > 0; off >>= 1) acc += __shfl_down(acc, off, 64);
  if (lane == 0) winv[row] = 1.0f / acc;
}

__global__ void __launch_bounds__(256) k_resample(uint32_t k0, uint32_t k1,
                                                  const float* __restrict__ winv,
                                                  int* __restrict__ idx) {
  uint32_t s = blockIdx.x;
  uint32_t base = s * (uint32_t)NP;
  const float TINY = 1.17549435e-38f;
  float best = 3.4e38f;
  int bi = 0;
#pragma unroll 4
  for (uint32_t i = threadIdx.x; i < NP; i += 256) {
    uint32_t bits = tf_bits(k0, k1, base + i);
    float v = fmaxf(u01(bits), TINY);
    float r = -__logf(v) * winv[i];
    if (r < best) { best = r; bi = (int)i; }
  }
  __shared__ float rv[256];
  __shared__ int ri[256];
  rv[threadIdx.x] = best;
  ri[threadIdx.x] = bi;
  __syncthreads();
  for (int stp = 128; stp > 0; stp >>= 1) {
    if (threadIdx.x < stp) {
      float va = rv[threadIdx.x], vb = rv[threadIdx.x + stp];
      int ia = ri[threadIdx.x], ib = ri[threadIdx.x + stp];
      if (vb < va || (vb == va && ib < ia)) { rv[threadIdx.x] = vb; ri[threadIdx.x] = ib; }
    }
    __syncthreads();
  }
  if (threadIdx.x == 0) idx[s] = ri[0];
}

// out = mean over s of state[idx[s]]
__global__ void __launch_bounds__(1024) k_mean(const float* __restrict__ st,
                                               const int* __restrict__ idx,
                                               float* __restrict__ out) {
  double a0 = 0, a1 = 0, a2 = 0;
  for (int s = threadIdx.x; s < NP; s += 1024) {
    int j = idx[s];
    a0 += st[j * 3];
    a1 += st[j * 3 + 1];
    a2 += st[j * 3 + 2];
  }
  __shared__ double r0[1024], r1[1024], r2[1024];
  r0[threadIdx.x] = a0; r1[threadIdx.x] = a1; r2[threadIdx.x] = a2;
  __syncthreads();
  for (int s = 512; s > 0; s >>= 1) {
    if (threadIdx.x < s) {
      r0[threadIdx.x] += r0[threadIdx.x + s];
      r1[threadIdx.x] += r1[threadIdx.x + s];
      r2[threadIdx.x] += r2[threadIdx.x + s];
    }
    __syncthreads();
  }
  if (threadIdx.x == 0) {
    out[0] = (float)(r0[0] / NP);
    out[1] = (float)(r1[0] / NP);
    out[2] = (float)(r2[0] / NP);
  }
}

extern "C" void kernel_launch(void* const* d_in, const int* in_sizes, int n_in,
                              void* d_out, int out_size, void* d_ws, size_t ws_size,
                              hipStream_t stream) {
  const float* in = (const float*)d_in[0];   // (1, C, P)
  const float* sv = (const float*)d_in[1];   // (P, 3)
  const float* T  = (const float*)d_in[2];   // (3, 3)
  const float* Q  = (const float*)d_in[3];   // (3, 3)
  const float* H  = (const float*)d_in[4];   // (C, 3)
  float* out = (float*)d_out;                // (3,)

  // partitionable split(key(42)): subkey j = threefry(key, (0, j)) both outputs
  uint32_t nk0, nk1, ck0, ck1;
  threefry2x32(0u, 42u, 0u, 0u, nk0, nk1);  // k_noise
  threefry2x32(0u, 42u, 0u, 1u, ck0, ck1);  // k_cat

  const size_t eFloats = (size_t)NP * (size_t)NP;        // 64M floats = 256 MB
  const size_t tailBytes = (24576 + 24576 + NP + NP) * 4; // st+ht+winv+idx
  const bool fused = ws_size >= eFloats * 4 + tailBytes;

  if (fused) {
    float* E    = (float*)d_ws;          // 256 MB
    float* st   = E + eFloats;           // 24576 f
    float* ht   = st + 24576;            // 24576 f
    float* winv = ht + 24576;            // 8192 f
    int*   idx  = (int*)(winv + NP);     // 8192 i

    hipLaunchKernelGGL(k_prep, dim3(128), dim3(256), 0, stream, nk0, nk1, sv, T, Q, H, st, ht);
    hipLaunchKernelGGL(k_fused, dim3(10240), dim3(256), 0, stream, ck0, ck1, in, ht, st, winv, E);
    hipLaunchKernelGGL(k_race, dim3(NP / 4), dim3(256), 0, stream, E, winv, idx);
    hipLaunchKernelGGL(k_mean, dim3(1), dim3(1024), 0, stream, st, idx, out);
  } else {
    float* st   = (float*)d_ws;          // 24576 f
    float* ht   = st + 24576;            // 24576 f
    float* winv = ht + 24576;            // 8192 f
    int*   idx  = (int*)(winv + NP);     // 8192 i

    hipLaunchKernelGGL(k_prep, dim3(128), dim3(256), 0, stream, nk0, nk1, sv, T, Q, H, st, ht);
    hipLaunchKernelGGL(k_weights, dim3(NP / 4), dim3(256), 0, stream, in, ht, st, winv);
    hipLaunchKernelGGL(k_resample, dim3(NP), dim3(256), 0, stream, ck0, ck1, winv, idx);
    hipLaunchKernelGGL(k_mean, dim3(1), dim3(1024), 0, stream, st, idx, out);
  }
}